// Round 1
// baseline (2245.102 us; speedup 1.0000x reference)
//
#include <hip/hip_runtime.h>
#include <math.h>

constexpr int IN_DIM = 1433;
constexpr int HID    = 16;
constexpr int OUTD   = 7;

// ---------- edge index access (int32 vs int64 auto-detect) ----------
// If data is int64 (little-endian, values < 2^31), dword 2*i is the value.
__device__ __forceinline__ int edge_get(const int* __restrict__ ei, int idx, int is64) {
    return is64 ? ei[2 * idx] : ei[idx];
}

__global__ void k_detect(const int* __restrict__ ei, int* __restrict__ flag) {
    __shared__ int nzsh;
    if (threadIdx.x == 0) nzsh = 0;
    __syncthreads();
    int nz = 0;
    for (int i = threadIdx.x; i < 2048; i += blockDim.x)
        nz |= (ei[2 * i + 1] != 0) ? 1 : 0;
    if (nz) nzsh = 1;           // benign race, any writer sets 1
    __syncthreads();
    if (threadIdx.x == 0) *flag = (nzsh == 0) ? 1 : 0;   // 1 => int64
}

// ---------- degree ----------
__global__ void k_deg_init(int* __restrict__ deg, int n) {
    int i = blockIdx.x * blockDim.x + threadIdx.x;
    if (i < n) deg[i] = 1;      // self loop
}

__global__ void k_deg_count(const int* __restrict__ ei, int E,
                            const int* __restrict__ flag, int* __restrict__ deg) {
    int e = blockIdx.x * blockDim.x + threadIdx.x;
    if (e >= E) return;
    int is64 = *flag;
    int s = edge_get(ei, e, is64);
    atomicAdd(&deg[s], 1);
}

__global__ void k_deg_finish(float* __restrict__ dis, int n) {
    int i = blockIdx.x * blockDim.x + threadIdx.x;
    if (i < n) {
        int v = ((const int*)dis)[i];
        dis[i] = rsqrtf((float)v);
    }
}

// ---------- GEMM1: h1 = x @ W1 + b1 ; a1 = dis^2 * h1 (self-loop init) ----------
// Block: 128 threads, tile 128 rows x 16 cols, BK=32.
// Thread t: colgroup c = t&3 (4 cols), rowthread rt = t>>2; rows rt+32*i, i<4.
__global__ __launch_bounds__(128) void k_gemm1(
        const float* __restrict__ x, const float* __restrict__ W1,
        const float* __restrict__ b1, const float* __restrict__ dis,
        float* __restrict__ h1, float* __restrict__ a1, int n) {
    __shared__ float xs[128 * 36];   // pad row stride to 36 floats (bank-safe)
    __shared__ float wsm[32 * 16];
    const int t   = threadIdx.x;
    const int c   = t & 3;
    const int rt  = t >> 2;
    const int row0 = blockIdx.x * 128;

    float acc[4][4];
    #pragma unroll
    for (int i = 0; i < 4; ++i)
        #pragma unroll
        for (int j = 0; j < 4; ++j) acc[i][j] = 0.f;

    for (int kt = 0; kt < IN_DIM; kt += 32) {
        // stage W1[kt..kt+31][0..15]
        #pragma unroll
        for (int u = 0; u < 4; ++u) {
            int idx = t * 4 + u;                 // 0..511
            int kk = idx >> 4;
            float v = 0.f;
            if (kt + kk < IN_DIM) v = W1[(kt + kk) * HID + (idx & 15)];
            wsm[idx] = v;
        }
        // stage x tile: 128 rows x 32 dwords; lanes read consecutive dwords (coalesced)
        #pragma unroll
        for (int rep = 0; rep < 32; ++rep) {
            int dnum = t + 128 * rep;            // 0..4095
            int r  = dnum >> 5;
            int kk = dnum & 31;
            int gr = row0 + r;
            float v = 0.f;
            if (gr < n && (kt + kk) < IN_DIM)
                v = x[(long long)gr * IN_DIM + kt + kk];
            xs[r * 36 + kk] = v;
        }
        __syncthreads();
        #pragma unroll
        for (int kk = 0; kk < 32; ++kk) {
            float4 w = *(const float4*)&wsm[kk * 16 + c * 4];
            #pragma unroll
            for (int i = 0; i < 4; ++i) {
                float xv = xs[(rt + 32 * i) * 36 + kk];
                acc[i][0] += xv * w.x;
                acc[i][1] += xv * w.y;
                acc[i][2] += xv * w.z;
                acc[i][3] += xv * w.w;
            }
        }
        __syncthreads();
    }
    float4 bv = *(const float4*)&b1[c * 4];
    #pragma unroll
    for (int i = 0; i < 4; ++i) {
        int gr = row0 + rt + 32 * i;
        if (gr < n) {
            float d = dis[gr];
            float dd = d * d;
            float4 hv;
            hv.x = acc[i][0] + bv.x;
            hv.y = acc[i][1] + bv.y;
            hv.z = acc[i][2] + bv.z;
            hv.w = acc[i][3] + bv.w;
            *(float4*)&h1[(long long)gr * 16 + c * 4] = hv;
            float4 av;
            av.x = dd * hv.x; av.y = dd * hv.y; av.z = dd * hv.z; av.w = dd * hv.w;
            *(float4*)&a1[(long long)gr * 16 + c * 4] = av;
        }
    }
}

// ---------- aggregation 1: a1[dst] += norm * h1[src], 16 feats, 4 threads/edge ----------
__global__ void k_agg1(const int* __restrict__ ei, int E, const int* __restrict__ flag,
                       const float* __restrict__ dis, const float* __restrict__ h1,
                       float* __restrict__ a1) {
    long long tid = (long long)blockIdx.x * blockDim.x + threadIdx.x;
    int e = (int)(tid >> 2);
    int q = (int)(tid & 3);
    if (e >= E) return;
    int is64 = *flag;
    int s = edge_get(ei, e, is64);
    int d = edge_get(ei, E + e, is64);
    float nrm = dis[s] * dis[d];
    float4 v = *(const float4*)&h1[(long long)s * 16 + q * 4];
    float* o = &a1[(long long)d * 16 + q * 4];
    atomicAdd(o + 0, nrm * v.x);
    atomicAdd(o + 1, nrm * v.y);
    atomicAdd(o + 2, nrm * v.z);
    atomicAdd(o + 3, nrm * v.w);
}

// ---------- GEMM2: h2 = relu(a1) @ W2 + b2 ; a2 = dis^2 * h2 ----------
__global__ __launch_bounds__(256) void k_gemm2(
        const float* __restrict__ a1, const float* __restrict__ W2,
        const float* __restrict__ b2, const float* __restrict__ dis,
        float* __restrict__ h2, float* __restrict__ a2, int n) {
    __shared__ float w2s[HID * OUTD];
    __shared__ float b2s[OUTD];
    int t = threadIdx.x;
    if (t < HID * OUTD) w2s[t] = W2[t];
    if (t < OUTD) b2s[t] = b2[t];
    __syncthreads();
    int r = blockIdx.x * blockDim.x + t;
    if (r >= n) return;
    float a[16];
    #pragma unroll
    for (int i = 0; i < 4; ++i) {
        float4 v = *(const float4*)&a1[(long long)r * 16 + i * 4];
        a[4 * i + 0] = fmaxf(v.x, 0.f);
        a[4 * i + 1] = fmaxf(v.y, 0.f);
        a[4 * i + 2] = fmaxf(v.z, 0.f);
        a[4 * i + 3] = fmaxf(v.w, 0.f);
    }
    float d = dis[r];
    float dd = d * d;
    #pragma unroll
    for (int j = 0; j < OUTD; ++j) {
        float acc = b2s[j];
        #pragma unroll
        for (int k = 0; k < HID; ++k) acc += a[k] * w2s[k * OUTD + j];
        h2[(long long)r * OUTD + j] = acc;
        a2[(long long)r * OUTD + j] = dd * acc;
    }
}

// ---------- aggregation 2: a2[dst] += norm * h2[src], 7 feats, 2 threads/edge ----------
__global__ void k_agg2(const int* __restrict__ ei, int E, const int* __restrict__ flag,
                       const float* __restrict__ dis, const float* __restrict__ h2,
                       float* __restrict__ a2) {
    long long tid = (long long)blockIdx.x * blockDim.x + threadIdx.x;
    int e = (int)(tid >> 1);
    int q = (int)(tid & 1);
    if (e >= E) return;
    int is64 = *flag;
    int s = edge_get(ei, e, is64);
    int d = edge_get(ei, E + e, is64);
    float nrm = dis[s] * dis[d];
    int cnt = q ? 3 : 4;
    long long bs = (long long)s * OUTD + q * 4;
    long long bd = (long long)d * OUTD + q * 4;
    #pragma unroll
    for (int j = 0; j < 4; ++j)
        if (j < cnt) atomicAdd(&a2[bd + j], nrm * h2[bs + j]);
}

// ---------- log_softmax over 7 classes ----------
__global__ void k_lsm(const float* __restrict__ a2, float* __restrict__ out, int n) {
    int r = blockIdx.x * blockDim.x + threadIdx.x;
    if (r >= n) return;
    float v[OUTD];
    #pragma unroll
    for (int j = 0; j < OUTD; ++j) v[j] = a2[(long long)r * OUTD + j];
    float m = v[0];
    #pragma unroll
    for (int j = 1; j < OUTD; ++j) m = fmaxf(m, v[j]);
    float ssum = 0.f;
    #pragma unroll
    for (int j = 0; j < OUTD; ++j) ssum += expf(v[j] - m);
    float l = logf(ssum);
    #pragma unroll
    for (int j = 0; j < OUTD; ++j) out[(long long)r * OUTD + j] = v[j] - m - l;
}

extern "C" void kernel_launch(void* const* d_in, const int* in_sizes, int n_in,
                              void* d_out, int out_size, void* d_ws, size_t ws_size,
                              hipStream_t stream) {
    const float* x  = (const float*)d_in[0];
    const int*   ei = (const int*)d_in[1];
    const float* W1 = (const float*)d_in[2];
    const float* b1 = (const float*)d_in[3];
    const float* W2 = (const float*)d_in[4];
    const float* b2 = (const float*)d_in[5];
    float* out = (float*)d_out;

    const int N = in_sizes[0] / IN_DIM;   // 100000
    const int E = in_sizes[1] / 2;        // 3200000

    // workspace layout (floats), 128-float (512 B) aligned chunks
    float* ws = (float*)d_ws;
    size_t o = 0;
    auto take = [&](size_t cnt) { size_t r = o; o += (cnt + 127) & ~(size_t)127; return r; };
    size_t off_dis  = take((size_t)N);
    size_t off_flag = take(64);
    size_t off_h1   = take((size_t)N * 16);
    size_t off_a1   = take((size_t)N * 16);
    size_t off_h2   = take((size_t)N * OUTD);
    size_t off_a2   = take((size_t)N * OUTD);

    float* dis  = ws + off_dis;
    int*   degi = (int*)dis;              // same buffer, int phase then float phase
    int*   flag = (int*)(ws + off_flag);
    float* h1   = ws + off_h1;
    float* a1   = ws + off_a1;
    float* h2   = ws + off_h2;
    float* a2   = ws + off_a2;

    const int TPB = 256;
    int gN   = (N + TPB - 1) / TPB;
    int gE   = (E + TPB - 1) / TPB;
    int g4E  = (int)(((long long)4 * E + TPB - 1) / TPB);
    int g2E  = (int)(((long long)2 * E + TPB - 1) / TPB);
    int gG1  = (N + 127) / 128;

    k_detect<<<1, 256, 0, stream>>>(ei, flag);
    k_deg_init<<<gN, TPB, 0, stream>>>(degi, N);
    k_deg_count<<<gE, TPB, 0, stream>>>(ei, E, flag, degi);
    k_deg_finish<<<gN, TPB, 0, stream>>>(dis, N);
    k_gemm1<<<gG1, 128, 0, stream>>>(x, W1, b1, dis, h1, a1, N);
    k_agg1<<<g4E, TPB, 0, stream>>>(ei, E, flag, dis, h1, a1);
    k_gemm2<<<gN, TPB, 0, stream>>>(a1, W2, b2, dis, h2, a2, N);
    k_agg2<<<g2E, TPB, 0, stream>>>(ei, E, flag, dis, h2, a2);
    k_lsm<<<gN, TPB, 0, stream>>>(a2, out, N);
}

// Round 2
// 2047.597 us; speedup vs baseline: 1.0965x; 1.0965x over previous
//
#include <hip/hip_runtime.h>
#include <math.h>

constexpr int IN_DIM = 1433;
constexpr int HID    = 16;
constexpr int OUTD   = 7;

// ---------- edge index access (int32 vs int64 auto-detect) ----------
// If data is int64 (little-endian, values < 2^31), dword 2*i is the value.
__device__ __forceinline__ int edge_get(const int* __restrict__ ei, int idx, int is64) {
    return is64 ? ei[2 * idx] : ei[idx];
}

__global__ void k_detect(const int* __restrict__ ei, int* __restrict__ flag) {
    __shared__ int nzsh;
    if (threadIdx.x == 0) nzsh = 0;
    __syncthreads();
    int nz = 0;
    for (int i = threadIdx.x; i < 2048; i += blockDim.x)
        nz |= (ei[2 * i + 1] != 0) ? 1 : 0;
    if (nz) nzsh = 1;           // benign race, any writer sets 1
    __syncthreads();
    if (threadIdx.x == 0) *flag = (nzsh == 0) ? 1 : 0;   // 1 => int64
}

// ---------- degree ----------
__global__ void k_deg_init(int* __restrict__ deg, int n) {
    int i = blockIdx.x * blockDim.x + threadIdx.x;
    if (i < n) deg[i] = 1;      // self loop
}

__global__ void k_deg_count(const int* __restrict__ ei, int E,
                            const int* __restrict__ flag, int* __restrict__ deg) {
    int e = blockIdx.x * blockDim.x + threadIdx.x;
    if (e >= E) return;
    int is64 = *flag;
    int s = edge_get(ei, e, is64);
    atomicAdd(&deg[s], 1);
}

__global__ void k_deg_finish(float* __restrict__ dis, int n) {
    int i = blockIdx.x * blockDim.x + threadIdx.x;
    if (i < n) {
        int v = ((const int*)dis)[i];
        dis[i] = rsqrtf((float)v);
    }
}

// ---------- GEMM1: h1 = x @ W1 + b1 ; a1 = dis^2 * h1 (self-loop init) ----------
// Block: 128 threads, tile 32 rows x 16 cols, BK=32. Grid = N/32 = 3125 blocks
// (12+ blocks/CU so stage/compute phases of different blocks overlap).
// Thread t: colgroup c = t&3 (4 cols), row rt = t>>2.
__global__ __launch_bounds__(128) void k_gemm1(
        const float* __restrict__ x, const float* __restrict__ W1,
        const float* __restrict__ b1, const float* __restrict__ dis,
        float* __restrict__ h1, float* __restrict__ a1, int n) {
    __shared__ float xs[32 * 33];    // stride 33 => read bank-stride 1, conflict-free
    __shared__ float wsm[32 * 16];
    const int t    = threadIdx.x;
    const int c    = t & 3;
    const int rt   = t >> 2;
    const int row0 = blockIdx.x * 32;

    float4 acc = make_float4(0.f, 0.f, 0.f, 0.f);

    for (int kt = 0; kt < IN_DIM; kt += 32) {
        // stage W1[kt..kt+31][0..15]; lane-consecutive writes (no bank conflict)
        #pragma unroll
        for (int u = 0; u < 4; ++u) {
            int idx = t + 128 * u;               // 0..511
            int kk = idx >> 4;
            float v = 0.f;
            if (kt + kk < IN_DIM) v = W1[(kt + kk) * HID + (idx & 15)];
            wsm[idx] = v;
        }
        // stage x tile: 32 rows x 32 dwords; lanes read consecutive dwords (coalesced)
        #pragma unroll
        for (int rep = 0; rep < 8; ++rep) {
            int dnum = t + 128 * rep;            // 0..1023
            int r  = dnum >> 5;
            int kk = dnum & 31;
            int gr = row0 + r;
            float v = 0.f;
            if (gr < n && (kt + kk) < IN_DIM)
                v = x[(long long)gr * IN_DIM + kt + kk];
            xs[r * 33 + kk] = v;
        }
        __syncthreads();
        #pragma unroll
        for (int kk = 0; kk < 32; ++kk) {
            float4 w = *(const float4*)&wsm[kk * 16 + c * 4];
            float xv = xs[rt * 33 + kk];
            acc.x += xv * w.x;
            acc.y += xv * w.y;
            acc.z += xv * w.z;
            acc.w += xv * w.w;
        }
        __syncthreads();
    }
    int gr = row0 + rt;
    if (gr < n) {
        float4 bv = *(const float4*)&b1[c * 4];
        float d = dis[gr];
        float dd = d * d;
        float4 hv;
        hv.x = acc.x + bv.x;
        hv.y = acc.y + bv.y;
        hv.z = acc.z + bv.z;
        hv.w = acc.w + bv.w;
        *(float4*)&h1[(long long)gr * 16 + c * 4] = hv;
        float4 av;
        av.x = dd * hv.x; av.y = dd * hv.y; av.z = dd * hv.z; av.w = dd * hv.w;
        *(float4*)&a1[(long long)gr * 16 + c * 4] = av;
    }
}

// ---------- aggregation 1: a1[dst] += norm * h1[src], 16 feats, 4 threads/edge ----------
__global__ void k_agg1(const int* __restrict__ ei, int E, const int* __restrict__ flag,
                       const float* __restrict__ dis, const float* __restrict__ h1,
                       float* __restrict__ a1) {
    long long tid = (long long)blockIdx.x * blockDim.x + threadIdx.x;
    int e = (int)(tid >> 2);
    int q = (int)(tid & 3);
    if (e >= E) return;
    int is64 = *flag;
    int s = edge_get(ei, e, is64);
    int d = edge_get(ei, E + e, is64);
    float nrm = dis[s] * dis[d];
    float4 v = *(const float4*)&h1[(long long)s * 16 + q * 4];
    float* o = &a1[(long long)d * 16 + q * 4];
    atomicAdd(o + 0, nrm * v.x);
    atomicAdd(o + 1, nrm * v.y);
    atomicAdd(o + 2, nrm * v.z);
    atomicAdd(o + 3, nrm * v.w);
}

// ---------- GEMM2: h2 = relu(a1) @ W2 + b2 ; a2 = dis^2 * h2 ----------
__global__ __launch_bounds__(256) void k_gemm2(
        const float* __restrict__ a1, const float* __restrict__ W2,
        const float* __restrict__ b2, const float* __restrict__ dis,
        float* __restrict__ h2, float* __restrict__ a2, int n) {
    __shared__ float w2s[HID * OUTD];
    __shared__ float b2s[OUTD];
    int t = threadIdx.x;
    if (t < HID * OUTD) w2s[t] = W2[t];
    if (t < OUTD) b2s[t] = b2[t];
    __syncthreads();
    int r = blockIdx.x * blockDim.x + t;
    if (r >= n) return;
    float a[16];
    #pragma unroll
    for (int i = 0; i < 4; ++i) {
        float4 v = *(const float4*)&a1[(long long)r * 16 + i * 4];
        a[4 * i + 0] = fmaxf(v.x, 0.f);
        a[4 * i + 1] = fmaxf(v.y, 0.f);
        a[4 * i + 2] = fmaxf(v.z, 0.f);
        a[4 * i + 3] = fmaxf(v.w, 0.f);
    }
    float d = dis[r];
    float dd = d * d;
    #pragma unroll
    for (int j = 0; j < OUTD; ++j) {
        float acc = b2s[j];
        #pragma unroll
        for (int k = 0; k < HID; ++k) acc += a[k] * w2s[k * OUTD + j];
        h2[(long long)r * OUTD + j] = acc;
        a2[(long long)r * OUTD + j] = dd * acc;
    }
}

// ---------- aggregation 2: a2[dst] += norm * h2[src], 7 feats, 2 threads/edge ----------
__global__ void k_agg2(const int* __restrict__ ei, int E, const int* __restrict__ flag,
                       const float* __restrict__ dis, const float* __restrict__ h2,
                       float* __restrict__ a2) {
    long long tid = (long long)blockIdx.x * blockDim.x + threadIdx.x;
    int e = (int)(tid >> 1);
    int q = (int)(tid & 1);
    if (e >= E) return;
    int is64 = *flag;
    int s = edge_get(ei, e, is64);
    int d = edge_get(ei, E + e, is64);
    float nrm = dis[s] * dis[d];
    int cnt = q ? 3 : 4;
    long long bs = (long long)s * OUTD + q * 4;
    long long bd = (long long)d * OUTD + q * 4;
    #pragma unroll
    for (int j = 0; j < 4; ++j)
        if (j < cnt) atomicAdd(&a2[bd + j], nrm * h2[bs + j]);
}

// ---------- log_softmax over 7 classes ----------
__global__ void k_lsm(const float* __restrict__ a2, float* __restrict__ out, int n) {
    int r = blockIdx.x * blockDim.x + threadIdx.x;
    if (r >= n) return;
    float v[OUTD];
    #pragma unroll
    for (int j = 0; j < OUTD; ++j) v[j] = a2[(long long)r * OUTD + j];
    float m = v[0];
    #pragma unroll
    for (int j = 1; j < OUTD; ++j) m = fmaxf(m, v[j]);
    float ssum = 0.f;
    #pragma unroll
    for (int j = 0; j < OUTD; ++j) ssum += expf(v[j] - m);
    float l = logf(ssum);
    #pragma unroll
    for (int j = 0; j < OUTD; ++j) out[(long long)r * OUTD + j] = v[j] - m - l;
}

extern "C" void kernel_launch(void* const* d_in, const int* in_sizes, int n_in,
                              void* d_out, int out_size, void* d_ws, size_t ws_size,
                              hipStream_t stream) {
    const float* x  = (const float*)d_in[0];
    const int*   ei = (const int*)d_in[1];
    const float* W1 = (const float*)d_in[2];
    const float* b1 = (const float*)d_in[3];
    const float* W2 = (const float*)d_in[4];
    const float* b2 = (const float*)d_in[5];
    float* out = (float*)d_out;

    const int N = in_sizes[0] / IN_DIM;   // 100000
    const int E = in_sizes[1] / 2;        // 3200000

    // workspace layout (floats), 128-float (512 B) aligned chunks
    float* ws = (float*)d_ws;
    size_t o = 0;
    auto take = [&](size_t cnt) { size_t r = o; o += (cnt + 127) & ~(size_t)127; return r; };
    size_t off_dis  = take((size_t)N);
    size_t off_flag = take(64);
    size_t off_h1   = take((size_t)N * 16);
    size_t off_a1   = take((size_t)N * 16);
    size_t off_h2   = take((size_t)N * OUTD);
    size_t off_a2   = take((size_t)N * OUTD);

    float* dis  = ws + off_dis;
    int*   degi = (int*)dis;              // same buffer, int phase then float phase
    int*   flag = (int*)(ws + off_flag);
    float* h1   = ws + off_h1;
    float* a1   = ws + off_a1;
    float* h2   = ws + off_h2;
    float* a2   = ws + off_a2;

    const int TPB = 256;
    int gN   = (N + TPB - 1) / TPB;
    int gE   = (E + TPB - 1) / TPB;
    int g4E  = (int)(((long long)4 * E + TPB - 1) / TPB);
    int g2E  = (int)(((long long)2 * E + TPB - 1) / TPB);
    int gG1  = (N + 31) / 32;

    k_detect<<<1, 256, 0, stream>>>(ei, flag);
    k_deg_init<<<gN, TPB, 0, stream>>>(degi, N);
    k_deg_count<<<gE, TPB, 0, stream>>>(ei, E, flag, degi);
    k_deg_finish<<<gN, TPB, 0, stream>>>(dis, N);
    k_gemm1<<<gG1, 128, 0, stream>>>(x, W1, b1, dis, h1, a1, N);
    k_agg1<<<g4E, TPB, 0, stream>>>(ei, E, flag, dis, h1, a1);
    k_gemm2<<<gN, TPB, 0, stream>>>(a1, W2, b2, dis, h2, a2, N);
    k_agg2<<<g2E, TPB, 0, stream>>>(ei, E, flag, dis, h2, a2);
    k_lsm<<<gN, TPB, 0, stream>>>(a2, out, N);
}

// Round 3
// 1195.936 us; speedup vs baseline: 1.8773x; 1.7121x over previous
//
#include <hip/hip_runtime.h>
#include <math.h>

constexpr int IN_DIM = 1433;
constexpr int HID    = 16;
constexpr int OUTD   = 7;

// ---------- edge index access (int32 vs int64 auto-detect) ----------
__device__ __forceinline__ int edge_get(const int* __restrict__ ei, long long idx, int is64) {
    return is64 ? ei[2 * idx] : ei[idx];
}

__global__ void k_detect(const int* __restrict__ ei, int* __restrict__ flag) {
    __shared__ int nzsh;
    if (threadIdx.x == 0) nzsh = 0;
    __syncthreads();
    int nz = 0;
    for (int i = threadIdx.x; i < 2048; i += blockDim.x)
        nz |= (ei[2 * i + 1] != 0) ? 1 : 0;
    if (nz) nzsh = 1;
    __syncthreads();
    if (threadIdx.x == 0) *flag = (nzsh == 0) ? 1 : 0;   // 1 => int64
}

// ---------- init / histogram ----------
__global__ void k_init_new(int* __restrict__ deg, int* __restrict__ cnt, int n) {
    int i = blockIdx.x * blockDim.x + threadIdx.x;
    if (i < n) { deg[i] = 1; cnt[i] = 0; }
}

__global__ void k_hist(const int* __restrict__ ei, int E, const int* __restrict__ flag,
                       int* __restrict__ deg, int* __restrict__ cnt) {
    int e = blockIdx.x * blockDim.x + threadIdx.x;
    if (e >= E) return;
    int is64 = *flag;
    int s = edge_get(ei, e, is64);
    int d = edge_get(ei, (long long)E + e, is64);
    atomicAdd(&deg[s], 1);   // degree on src (reference semantics)
    atomicAdd(&cnt[d], 1);   // CSR bucket sizes by dst
}

__global__ void k_deg_finish(float* __restrict__ dis, int n) {
    int i = blockIdx.x * blockDim.x + threadIdx.x;
    if (i < n) {
        int v = ((const int*)dis)[i];
        dis[i] = rsqrtf((float)v);
    }
}

// ---------- 3-kernel exclusive scan of cnt[0..n) -> row_ptr, cursor ----------
// chunk = 1024 elements per block (256 threads x 4)
__global__ __launch_bounds__(256) void k_scan1(const int* __restrict__ cnt,
                                               int* __restrict__ bsum, int n) {
    __shared__ int sh[256];
    int t = threadIdx.x;
    int base = blockIdx.x * 1024 + t * 4;
    int s = 0;
    #pragma unroll
    for (int j = 0; j < 4; ++j) {
        int i = base + j;
        if (i < n) s += cnt[i];
    }
    sh[t] = s; __syncthreads();
    for (int o = 128; o > 0; o >>= 1) {
        if (t < o) sh[t] += sh[t + o];
        __syncthreads();
    }
    if (t == 0) bsum[blockIdx.x] = sh[0];
}

__global__ __launch_bounds__(256) void k_scan2(const int* __restrict__ bsum,
                                               int* __restrict__ boff,
                                               int* __restrict__ rp,
                                               int nb, int n, int E) {
    __shared__ int sh[256];
    int t = threadIdx.x;
    int v = (t < nb) ? bsum[t] : 0;
    sh[t] = v; __syncthreads();
    for (int o = 1; o < 256; o <<= 1) {
        int tmp = (t >= o) ? sh[t - o] : 0;
        __syncthreads();
        sh[t] += tmp;
        __syncthreads();
    }
    boff[t] = sh[t] - v;     // exclusive
    if (t == 0) rp[n] = E;   // total
}

__global__ __launch_bounds__(256) void k_scan3(const int* __restrict__ cnt,
                                               const int* __restrict__ boff,
                                               int* __restrict__ rp,
                                               int* __restrict__ cur, int n) {
    __shared__ int sh[256];
    int t = threadIdx.x;
    int base = blockIdx.x * 1024 + t * 4;
    int c[4];
    int s = 0;
    #pragma unroll
    for (int j = 0; j < 4; ++j) {
        int i = base + j;
        c[j] = (i < n) ? cnt[i] : 0;
        s += c[j];
    }
    sh[t] = s; __syncthreads();
    for (int o = 1; o < 256; o <<= 1) {
        int tmp = (t >= o) ? sh[t - o] : 0;
        __syncthreads();
        sh[t] += tmp;
        __syncthreads();
    }
    int run = boff[blockIdx.x] + sh[t] - s;   // exclusive prefix for this thread
    #pragma unroll
    for (int j = 0; j < 4; ++j) {
        int i = base + j;
        if (i < n) { rp[i] = run; cur[i] = run; }
        run += c[j];
    }
}

__global__ void k_fill(const int* __restrict__ ei, int E, const int* __restrict__ flag,
                       int* __restrict__ cur, int* __restrict__ csr) {
    int e = blockIdx.x * blockDim.x + threadIdx.x;
    if (e >= E) return;
    int is64 = *flag;
    int s = edge_get(ei, e, is64);
    int d = edge_get(ei, (long long)E + e, is64);
    int slot = atomicAdd(&cur[d], 1);
    csr[slot] = s;
}

// ---------- GEMM1: h1 = x @ W1 + b1 (+ optional a1 = dis^2*h1 for fallback) ----------
__global__ __launch_bounds__(128) void k_gemm1(
        const float* __restrict__ x, const float* __restrict__ W1,
        const float* __restrict__ b1, const float* __restrict__ dis,
        float* __restrict__ h1, float* __restrict__ a1, int n) {
    __shared__ float xs[32 * 33];
    __shared__ float wsm[32 * 16];
    const int t    = threadIdx.x;
    const int c    = t & 3;
    const int rt   = t >> 2;
    const int row0 = blockIdx.x * 32;

    float4 acc = make_float4(0.f, 0.f, 0.f, 0.f);

    for (int kt = 0; kt < IN_DIM; kt += 32) {
        #pragma unroll
        for (int u = 0; u < 4; ++u) {
            int idx = t + 128 * u;
            int kk = idx >> 4;
            float v = 0.f;
            if (kt + kk < IN_DIM) v = W1[(kt + kk) * HID + (idx & 15)];
            wsm[idx] = v;
        }
        #pragma unroll
        for (int rep = 0; rep < 8; ++rep) {
            int dnum = t + 128 * rep;
            int r  = dnum >> 5;
            int kk = dnum & 31;
            int gr = row0 + r;
            float v = 0.f;
            if (gr < n && (kt + kk) < IN_DIM)
                v = x[(long long)gr * IN_DIM + kt + kk];
            xs[r * 33 + kk] = v;
        }
        __syncthreads();
        #pragma unroll
        for (int kk = 0; kk < 32; ++kk) {
            float4 w = *(const float4*)&wsm[kk * 16 + c * 4];
            float xv = xs[rt * 33 + kk];
            acc.x += xv * w.x;
            acc.y += xv * w.y;
            acc.z += xv * w.z;
            acc.w += xv * w.w;
        }
        __syncthreads();
    }
    int gr = row0 + rt;
    if (gr < n) {
        float4 bv = *(const float4*)&b1[c * 4];
        float4 hv;
        hv.x = acc.x + bv.x;
        hv.y = acc.y + bv.y;
        hv.z = acc.z + bv.z;
        hv.w = acc.w + bv.w;
        *(float4*)&h1[(long long)gr * 16 + c * 4] = hv;
        if (a1) {
            float d = dis[gr];
            float dd = d * d;
            float4 av;
            av.x = dd * hv.x; av.y = dd * hv.y; av.z = dd * hv.z; av.w = dd * hv.w;
            *(float4*)&a1[(long long)gr * 16 + c * 4] = av;
        }
    }
}

// ---------- gather aggregation 1: a1[v] = dis[v]^2*h1[v] + sum norm*h1[src] ----------
// 16 threads per node (one per feature)
__global__ __launch_bounds__(256) void k_gather1(
        const int* __restrict__ rp, const int* __restrict__ csr,
        const float* __restrict__ dis, const float* __restrict__ h1,
        float* __restrict__ a1, int n) {
    int t = threadIdx.x;
    int node = blockIdx.x * 16 + (t >> 4);
    int q = t & 15;
    if (node >= n) return;
    float dn = dis[node];
    float acc = dn * dn * h1[(long long)node * 16 + q];
    int beg = rp[node], end = rp[node + 1];
    for (int i = beg; i < end; ++i) {
        int s = csr[i];
        acc += dn * dis[s] * h1[(long long)s * 16 + q];
    }
    a1[(long long)node * 16 + q] = acc;
}

// ---------- GEMM2: h2 = relu(a1) @ W2 + b2 (+ optional a2 for fallback) ----------
__global__ __launch_bounds__(256) void k_gemm2(
        const float* __restrict__ a1, const float* __restrict__ W2,
        const float* __restrict__ b2, const float* __restrict__ dis,
        float* __restrict__ h2, float* __restrict__ a2, int n) {
    __shared__ float w2s[HID * OUTD];
    __shared__ float b2s[OUTD];
    int t = threadIdx.x;
    if (t < HID * OUTD) w2s[t] = W2[t];
    if (t < OUTD) b2s[t] = b2[t];
    __syncthreads();
    int r = blockIdx.x * blockDim.x + t;
    if (r >= n) return;
    float a[16];
    #pragma unroll
    for (int i = 0; i < 4; ++i) {
        float4 v = *(const float4*)&a1[(long long)r * 16 + i * 4];
        a[4 * i + 0] = fmaxf(v.x, 0.f);
        a[4 * i + 1] = fmaxf(v.y, 0.f);
        a[4 * i + 2] = fmaxf(v.z, 0.f);
        a[4 * i + 3] = fmaxf(v.w, 0.f);
    }
    float dd = 0.f;
    if (a2) { float d = dis[r]; dd = d * d; }
    #pragma unroll
    for (int j = 0; j < OUTD; ++j) {
        float acc = b2s[j];
        #pragma unroll
        for (int k = 0; k < HID; ++k) acc += a[k] * w2s[k * OUTD + j];
        h2[(long long)r * OUTD + j] = acc;
        if (a2) a2[(long long)r * OUTD + j] = dd * acc;
    }
}

// ---------- gather aggregation 2 + log_softmax fused ----------
// 8 threads per node (7 features + 1 idle lane), shfl reductions within 8-lane group
__global__ __launch_bounds__(256) void k_gather2(
        const int* __restrict__ rp, const int* __restrict__ csr,
        const float* __restrict__ dis, const float* __restrict__ h2,
        float* __restrict__ out, int n) {
    int t = threadIdx.x;
    int node = blockIdx.x * 32 + (t >> 3);
    int q = t & 7;
    if (node >= n) return;
    float dn = dis[node];
    float acc = -1e30f;
    if (q < OUTD) {
        acc = dn * dn * h2[(long long)node * OUTD + q];
        int beg = rp[node], end = rp[node + 1];
        for (int i = beg; i < end; ++i) {
            int s = csr[i];
            acc += dn * dis[s] * h2[(long long)s * OUTD + q];
        }
    }
    float m = acc;
    #pragma unroll
    for (int o = 1; o < 8; o <<= 1) m = fmaxf(m, __shfl_xor(m, o, 8));
    float ex = (q < OUTD) ? expf(acc - m) : 0.f;
    float ss = ex;
    #pragma unroll
    for (int o = 1; o < 8; o <<= 1) ss += __shfl_xor(ss, o, 8);
    if (q < OUTD) out[(long long)node * OUTD + q] = acc - m - logf(ss);
}

// ---------- fallback-only kernels (round-2 atomic path) ----------
__global__ void k_deg_init(int* __restrict__ deg, int n) {
    int i = blockIdx.x * blockDim.x + threadIdx.x;
    if (i < n) deg[i] = 1;
}

__global__ void k_deg_count(const int* __restrict__ ei, int E,
                            const int* __restrict__ flag, int* __restrict__ deg) {
    int e = blockIdx.x * blockDim.x + threadIdx.x;
    if (e >= E) return;
    int is64 = *flag;
    int s = edge_get(ei, e, is64);
    atomicAdd(&deg[s], 1);
}

__global__ void k_agg1(const int* __restrict__ ei, int E, const int* __restrict__ flag,
                       const float* __restrict__ dis, const float* __restrict__ h1,
                       float* __restrict__ a1) {
    long long tid = (long long)blockIdx.x * blockDim.x + threadIdx.x;
    int e = (int)(tid >> 2);
    int q = (int)(tid & 3);
    if (e >= E) return;
    int is64 = *flag;
    int s = edge_get(ei, e, is64);
    int d = edge_get(ei, (long long)E + e, is64);
    float nrm = dis[s] * dis[d];
    float4 v = *(const float4*)&h1[(long long)s * 16 + q * 4];
    float* o = &a1[(long long)d * 16 + q * 4];
    atomicAdd(o + 0, nrm * v.x);
    atomicAdd(o + 1, nrm * v.y);
    atomicAdd(o + 2, nrm * v.z);
    atomicAdd(o + 3, nrm * v.w);
}

__global__ void k_agg2(const int* __restrict__ ei, int E, const int* __restrict__ flag,
                       const float* __restrict__ dis, const float* __restrict__ h2,
                       float* __restrict__ a2) {
    long long tid = (long long)blockIdx.x * blockDim.x + threadIdx.x;
    int e = (int)(tid >> 1);
    int q = (int)(tid & 1);
    if (e >= E) return;
    int is64 = *flag;
    int s = edge_get(ei, e, is64);
    int d = edge_get(ei, (long long)E + e, is64);
    float nrm = dis[s] * dis[d];
    int cnt = q ? 3 : 4;
    long long bs = (long long)s * OUTD + q * 4;
    long long bd = (long long)d * OUTD + q * 4;
    #pragma unroll
    for (int j = 0; j < 4; ++j)
        if (j < cnt) atomicAdd(&a2[bd + j], nrm * h2[bs + j]);
}

__global__ void k_lsm(const float* __restrict__ a2, float* __restrict__ out, int n) {
    int r = blockIdx.x * blockDim.x + threadIdx.x;
    if (r >= n) return;
    float v[OUTD];
    #pragma unroll
    for (int j = 0; j < OUTD; ++j) v[j] = a2[(long long)r * OUTD + j];
    float m = v[0];
    #pragma unroll
    for (int j = 1; j < OUTD; ++j) m = fmaxf(m, v[j]);
    float ssum = 0.f;
    #pragma unroll
    for (int j = 0; j < OUTD; ++j) ssum += expf(v[j] - m);
    float l = logf(ssum);
    #pragma unroll
    for (int j = 0; j < OUTD; ++j) out[(long long)r * OUTD + j] = v[j] - m - l;
}

extern "C" void kernel_launch(void* const* d_in, const int* in_sizes, int n_in,
                              void* d_out, int out_size, void* d_ws, size_t ws_size,
                              hipStream_t stream) {
    const float* x  = (const float*)d_in[0];
    const int*   ei = (const int*)d_in[1];
    const float* W1 = (const float*)d_in[2];
    const float* b1 = (const float*)d_in[3];
    const float* W2 = (const float*)d_in[4];
    const float* b2 = (const float*)d_in[5];
    float* out = (float*)d_out;

    const int N = in_sizes[0] / IN_DIM;   // 100000
    const int E = in_sizes[1] / 2;        // 3200000

    const int TPB = 256;
    const int gN  = (N + TPB - 1) / TPB;
    const int gE  = (E + TPB - 1) / TPB;
    const int gG1 = (N + 31) / 32;
    const int NB  = (N + 1023) / 1024;    // scan blocks (<=256)

    float* ws = (float*)d_ws;
    size_t o = 0;
    auto take = [&](size_t cnt) { size_t r = o; o += (cnt + 127) & ~(size_t)127; return r; };

    // ---- new-path layout ----
    size_t off_dis  = take((size_t)N);
    size_t off_flag = take(64);
    size_t off_cnt  = take((size_t)N);
    size_t off_rp   = take((size_t)N + 1);
    size_t off_cur  = take((size_t)N);
    size_t off_bs   = take(256);
    size_t off_bo   = take(256);
    size_t off_csr  = take((size_t)E);
    size_t off_h1   = take((size_t)N * 16);
    size_t off_a1   = take((size_t)N * 16);
    size_t off_h2   = take((size_t)N * OUTD);
    size_t need_new = o * sizeof(float);

    if (ws_size >= need_new) {
        float* dis  = ws + off_dis;
        int*   degi = (int*)dis;
        int*   flag = (int*)(ws + off_flag);
        int*   cnt  = (int*)(ws + off_cnt);
        int*   rp   = (int*)(ws + off_rp);
        int*   cur  = (int*)(ws + off_cur);
        int*   bs   = (int*)(ws + off_bs);
        int*   bo   = (int*)(ws + off_bo);
        int*   csr  = (int*)(ws + off_csr);
        float* h1   = ws + off_h1;
        float* a1   = ws + off_a1;
        float* h2   = ws + off_h2;

        k_detect<<<1, 256, 0, stream>>>(ei, flag);
        k_init_new<<<gN, TPB, 0, stream>>>(degi, cnt, N);
        k_hist<<<gE, TPB, 0, stream>>>(ei, E, flag, degi, cnt);
        k_deg_finish<<<gN, TPB, 0, stream>>>(dis, N);
        k_scan1<<<NB, 256, 0, stream>>>(cnt, bs, N);
        k_scan2<<<1, 256, 0, stream>>>(bs, bo, rp, NB, N, E);
        k_scan3<<<NB, 256, 0, stream>>>(cnt, bo, rp, cur, N);
        k_fill<<<gE, TPB, 0, stream>>>(ei, E, flag, cur, csr);
        k_gemm1<<<gG1, 128, 0, stream>>>(x, W1, b1, dis, h1, nullptr, N);
        k_gather1<<<(N + 15) / 16, 256, 0, stream>>>(rp, csr, dis, h1, a1, N);
        k_gemm2<<<gN, TPB, 0, stream>>>(a1, W2, b2, dis, h2, nullptr, N);
        k_gather2<<<(N + 31) / 32, 256, 0, stream>>>(rp, csr, dis, h2, out, N);
    } else {
        // ---- fallback: round-2 atomic path ----
        o = 0;
        size_t f_dis  = take((size_t)N);
        size_t f_flag = take(64);
        size_t f_h1   = take((size_t)N * 16);
        size_t f_a1   = take((size_t)N * 16);
        size_t f_h2   = take((size_t)N * OUTD);
        size_t f_a2   = take((size_t)N * OUTD);

        float* dis  = ws + f_dis;
        int*   degi = (int*)dis;
        int*   flag = (int*)(ws + f_flag);
        float* h1   = ws + f_h1;
        float* a1   = ws + f_a1;
        float* h2   = ws + f_h2;
        float* a2   = ws + f_a2;

        int g4E = (int)(((long long)4 * E + TPB - 1) / TPB);
        int g2E = (int)(((long long)2 * E + TPB - 1) / TPB);

        k_detect<<<1, 256, 0, stream>>>(ei, flag);
        k_deg_init<<<gN, TPB, 0, stream>>>(degi, N);
        k_deg_count<<<gE, TPB, 0, stream>>>(ei, E, flag, degi);
        k_deg_finish<<<gN, TPB, 0, stream>>>(dis, N);
        k_gemm1<<<gG1, 128, 0, stream>>>(x, W1, b1, dis, h1, a1, N);
        k_agg1<<<g4E, TPB, 0, stream>>>(ei, E, flag, dis, h1, a1);
        k_gemm2<<<gN, TPB, 0, stream>>>(a1, W2, b2, dis, h2, a2, N);
        k_agg2<<<g2E, TPB, 0, stream>>>(ei, E, flag, dis, h2, a2);
        k_lsm<<<gN, TPB, 0, stream>>>(a2, out, N);
    }
}

// Round 4
// 853.539 us; speedup vs baseline: 2.6303x; 1.4011x over previous
//
#include <hip/hip_runtime.h>
#include <math.h>

constexpr int IN_DIM = 1433;
constexpr int HID    = 16;
constexpr int OUTD   = 7;

// ---------- edge index access (int32 vs int64 auto-detect) ----------
__device__ __forceinline__ int edge_get(const int* __restrict__ ei, long long idx, int is64) {
    return is64 ? ei[2 * idx] : ei[idx];
}

__global__ void k_detect(const int* __restrict__ ei, int* __restrict__ flag) {
    __shared__ int nzsh;
    if (threadIdx.x == 0) nzsh = 0;
    __syncthreads();
    int nz = 0;
    for (int i = threadIdx.x; i < 2048; i += blockDim.x)
        nz |= (ei[2 * i + 1] != 0) ? 1 : 0;
    if (nz) nzsh = 1;
    __syncthreads();
    if (threadIdx.x == 0) *flag = (nzsh == 0) ? 1 : 0;   // 1 => int64
}

// ---------- init / histogram ----------
__global__ void k_init_new(int* __restrict__ deg, int* __restrict__ cnt, int n) {
    int i = blockIdx.x * blockDim.x + threadIdx.x;
    if (i < n) { deg[i] = 1; cnt[i] = 0; }
}

__global__ void k_hist(const int* __restrict__ ei, int E, const int* __restrict__ flag,
                       int* __restrict__ deg, int* __restrict__ cnt) {
    int e = blockIdx.x * blockDim.x + threadIdx.x;
    if (e >= E) return;
    int is64 = *flag;
    int s = edge_get(ei, e, is64);
    int d = edge_get(ei, (long long)E + e, is64);
    atomicAdd(&deg[s], 1);   // degree on src (reference semantics)
    atomicAdd(&cnt[d], 1);   // CSR bucket sizes by dst
}

__global__ void k_deg_finish(float* __restrict__ dis, int n) {
    int i = blockIdx.x * blockDim.x + threadIdx.x;
    if (i < n) {
        int v = ((const int*)dis)[i];
        dis[i] = rsqrtf((float)v);
    }
}

// ---------- 3-kernel exclusive scan of cnt[0..n) -> row_ptr, cursor ----------
__global__ __launch_bounds__(256) void k_scan1(const int* __restrict__ cnt,
                                               int* __restrict__ bsum, int n) {
    __shared__ int sh[256];
    int t = threadIdx.x;
    int base = blockIdx.x * 1024 + t * 4;
    int s = 0;
    #pragma unroll
    for (int j = 0; j < 4; ++j) {
        int i = base + j;
        if (i < n) s += cnt[i];
    }
    sh[t] = s; __syncthreads();
    for (int o = 128; o > 0; o >>= 1) {
        if (t < o) sh[t] += sh[t + o];
        __syncthreads();
    }
    if (t == 0) bsum[blockIdx.x] = sh[0];
}

__global__ __launch_bounds__(256) void k_scan2(const int* __restrict__ bsum,
                                               int* __restrict__ boff,
                                               int* __restrict__ rp,
                                               int nb, int n, int E) {
    __shared__ int sh[256];
    int t = threadIdx.x;
    int v = (t < nb) ? bsum[t] : 0;
    sh[t] = v; __syncthreads();
    for (int o = 1; o < 256; o <<= 1) {
        int tmp = (t >= o) ? sh[t - o] : 0;
        __syncthreads();
        sh[t] += tmp;
        __syncthreads();
    }
    boff[t] = sh[t] - v;     // exclusive
    if (t == 0) rp[n] = E;   // total
}

__global__ __launch_bounds__(256) void k_scan3(const int* __restrict__ cnt,
                                               const int* __restrict__ boff,
                                               int* __restrict__ rp,
                                               int* __restrict__ cur, int n) {
    __shared__ int sh[256];
    int t = threadIdx.x;
    int base = blockIdx.x * 1024 + t * 4;
    int c[4];
    int s = 0;
    #pragma unroll
    for (int j = 0; j < 4; ++j) {
        int i = base + j;
        c[j] = (i < n) ? cnt[i] : 0;
        s += c[j];
    }
    sh[t] = s; __syncthreads();
    for (int o = 1; o < 256; o <<= 1) {
        int tmp = (t >= o) ? sh[t - o] : 0;
        __syncthreads();
        sh[t] += tmp;
        __syncthreads();
    }
    int run = boff[blockIdx.x] + sh[t] - s;
    #pragma unroll
    for (int j = 0; j < 4; ++j) {
        int i = base + j;
        if (i < n) { rp[i] = run; cur[i] = run; }
        run += c[j];
    }
}

__global__ void k_fill(const int* __restrict__ ei, int E, const int* __restrict__ flag,
                       int* __restrict__ cur, int* __restrict__ csr) {
    int e = blockIdx.x * blockDim.x + threadIdx.x;
    if (e >= E) return;
    int is64 = *flag;
    int s = edge_get(ei, e, is64);
    int d = edge_get(ei, (long long)E + e, is64);
    int slot = atomicAdd(&cur[d], 1);
    csr[slot] = s;
}

// ---------- GEMM1: h1 = x @ W1 + b1 (+ optional a1 = dis^2*h1) ----------
// BM=64 rows x 16 cols, BK=128. 256 threads (4 waves).
// Staging: wave w loads rows [w*16, w*16+16), 2 lane-consecutive 256B instrs
// per row (512B contiguous per row per chunk), into registers; ds_write after
// barrier; NEXT chunk's loads issue before compute so FMA hides HBM latency.
__global__ __launch_bounds__(256) void k_gemm1(
        const float* __restrict__ x, const float* __restrict__ W1,
        const float* __restrict__ b1, const float* __restrict__ dis,
        float* __restrict__ h1, float* __restrict__ a1, int n) {
    constexpr int BM = 64, BK = 128;
    __shared__ __align__(16) float xs[BM * 132];   // stride 132: b128 reads 2-way max
    __shared__ __align__(16) float wsm[BK * 16];
    const int t   = threadIdx.x;
    const int wv  = t >> 6;          // wave 0..3
    const int ln  = t & 63;
    const int cr  = t >> 2;          // output row 0..63
    const int c4  = t & 3;           // col group (4 cols)
    const int row0 = blockIdx.x * BM;

    float xreg[32];
    float wreg[8];
    float acc[4] = {0.f, 0.f, 0.f, 0.f};

    auto issue_loads = [&](int kt) {
        #pragma unroll
        for (int rr = 0; rr < 16; ++rr) {
            int gr = row0 + wv * 16 + rr;
            const float* rowp = x + (long long)gr * IN_DIM;
            #pragma unroll
            for (int h = 0; h < 2; ++h) {
                int col = kt + h * 64 + ln;
                float v = 0.f;
                if (gr < n && col < IN_DIM) v = rowp[col];
                xreg[rr * 2 + h] = v;
            }
        }
        #pragma unroll
        for (int u = 0; u < 8; ++u) {
            int idx = t + 256 * u;            // 0..2047
            int kk  = idx >> 4;
            float v = 0.f;
            if (kt + kk < IN_DIM) v = W1[(kt + kk) * HID + (idx & 15)];
            wreg[u] = v;
        }
    };
    auto write_lds = [&]() {
        #pragma unroll
        for (int rr = 0; rr < 16; ++rr)
            #pragma unroll
            for (int h = 0; h < 2; ++h)
                xs[(wv * 16 + rr) * 132 + h * 64 + ln] = xreg[rr * 2 + h];
        #pragma unroll
        for (int u = 0; u < 8; ++u)
            wsm[t + 256 * u] = wreg[u];
    };

    issue_loads(0);
    for (int kt = 0; kt < IN_DIM; kt += BK) {
        write_lds();
        __syncthreads();
        if (kt + BK < IN_DIM) issue_loads(kt + BK);   // overlaps with compute
        #pragma unroll 8
        for (int k = 0; k < BK; k += 4) {
            float4 xv = *(const float4*)&xs[cr * 132 + k];
            #pragma unroll
            for (int s = 0; s < 4; ++s) {
                float4 w = *(const float4*)&wsm[(k + s) * HID + c4 * 4];
                float xe = (s == 0) ? xv.x : (s == 1) ? xv.y : (s == 2) ? xv.z : xv.w;
                acc[0] += xe * w.x;
                acc[1] += xe * w.y;
                acc[2] += xe * w.z;
                acc[3] += xe * w.w;
            }
        }
        __syncthreads();
    }

    int gr = row0 + cr;
    if (gr < n) {
        float4 bv = *(const float4*)&b1[c4 * 4];
        float4 hv;
        hv.x = acc[0] + bv.x;
        hv.y = acc[1] + bv.y;
        hv.z = acc[2] + bv.z;
        hv.w = acc[3] + bv.w;
        *(float4*)&h1[(long long)gr * HID + c4 * 4] = hv;
        if (a1) {
            float d = dis[gr];
            float dd = d * d;
            float4 av;
            av.x = dd * hv.x; av.y = dd * hv.y; av.z = dd * hv.z; av.w = dd * hv.w;
            *(float4*)&a1[(long long)gr * HID + c4 * 4] = av;
        }
    }
}

// ---------- gather aggregation 1: a1[v] = dis[v]^2*h1[v] + sum norm*h1[src] ----------
// 4 threads per node, float4 per lane
__global__ __launch_bounds__(256) void k_gather1(
        const int* __restrict__ rp, const int* __restrict__ csr,
        const float* __restrict__ dis, const float* __restrict__ h1,
        float* __restrict__ a1, int n) {
    int tid = blockIdx.x * blockDim.x + threadIdx.x;
    int node = tid >> 2;
    int q = tid & 3;
    if (node >= n) return;
    float dn = dis[node];
    float4 v = *(const float4*)&h1[(long long)node * HID + q * 4];
    float dd = dn * dn;
    float4 acc;
    acc.x = dd * v.x; acc.y = dd * v.y; acc.z = dd * v.z; acc.w = dd * v.w;
    int beg = rp[node], end = rp[node + 1];
    for (int i = beg; i < end; ++i) {
        int s = csr[i];
        float nrm = dn * dis[s];
        float4 hv = *(const float4*)&h1[(long long)s * HID + q * 4];
        acc.x += nrm * hv.x;
        acc.y += nrm * hv.y;
        acc.z += nrm * hv.z;
        acc.w += nrm * hv.w;
    }
    *(float4*)&a1[(long long)node * HID + q * 4] = acc;
}

// ---------- GEMM2: h2 = relu(a1) @ W2 + b2 (+ optional a2 for fallback) ----------
__global__ __launch_bounds__(256) void k_gemm2(
        const float* __restrict__ a1, const float* __restrict__ W2,
        const float* __restrict__ b2, const float* __restrict__ dis,
        float* __restrict__ h2, float* __restrict__ a2, int n) {
    __shared__ float w2s[HID * OUTD];
    __shared__ float b2s[OUTD];
    int t = threadIdx.x;
    if (t < HID * OUTD) w2s[t] = W2[t];
    if (t < OUTD) b2s[t] = b2[t];
    __syncthreads();
    int r = blockIdx.x * blockDim.x + t;
    if (r >= n) return;
    float a[16];
    #pragma unroll
    for (int i = 0; i < 4; ++i) {
        float4 v = *(const float4*)&a1[(long long)r * HID + i * 4];
        a[4 * i + 0] = fmaxf(v.x, 0.f);
        a[4 * i + 1] = fmaxf(v.y, 0.f);
        a[4 * i + 2] = fmaxf(v.z, 0.f);
        a[4 * i + 3] = fmaxf(v.w, 0.f);
    }
    float dd = 0.f;
    if (a2) { float d = dis[r]; dd = d * d; }
    #pragma unroll
    for (int j = 0; j < OUTD; ++j) {
        float acc = b2s[j];
        #pragma unroll
        for (int k = 0; k < HID; ++k) acc += a[k] * w2s[k * OUTD + j];
        h2[(long long)r * OUTD + j] = acc;
        if (a2) a2[(long long)r * OUTD + j] = dd * acc;
    }
}

// ---------- gather aggregation 2 + log_softmax fused ----------
__global__ __launch_bounds__(256) void k_gather2(
        const int* __restrict__ rp, const int* __restrict__ csr,
        const float* __restrict__ dis, const float* __restrict__ h2,
        float* __restrict__ out, int n) {
    int t = threadIdx.x;
    int node = blockIdx.x * 32 + (t >> 3);
    int q = t & 7;
    if (node >= n) return;
    float dn = dis[node];
    float acc = -1e30f;
    if (q < OUTD) {
        acc = dn * dn * h2[(long long)node * OUTD + q];
        int beg = rp[node], end = rp[node + 1];
        for (int i = beg; i < end; ++i) {
            int s = csr[i];
            acc += dn * dis[s] * h2[(long long)s * OUTD + q];
        }
    }
    float m = acc;
    #pragma unroll
    for (int o = 1; o < 8; o <<= 1) m = fmaxf(m, __shfl_xor(m, o, 8));
    float ex = (q < OUTD) ? expf(acc - m) : 0.f;
    float ss = ex;
    #pragma unroll
    for (int o = 1; o < 8; o <<= 1) ss += __shfl_xor(ss, o, 8);
    if (q < OUTD) out[(long long)node * OUTD + q] = acc - m - logf(ss);
}

// ---------- fallback-only kernels (atomic path) ----------
__global__ void k_deg_init(int* __restrict__ deg, int n) {
    int i = blockIdx.x * blockDim.x + threadIdx.x;
    if (i < n) deg[i] = 1;
}

__global__ void k_deg_count(const int* __restrict__ ei, int E,
                            const int* __restrict__ flag, int* __restrict__ deg) {
    int e = blockIdx.x * blockDim.x + threadIdx.x;
    if (e >= E) return;
    int is64 = *flag;
    int s = edge_get(ei, e, is64);
    atomicAdd(&deg[s], 1);
}

__global__ void k_agg1(const int* __restrict__ ei, int E, const int* __restrict__ flag,
                       const float* __restrict__ dis, const float* __restrict__ h1,
                       float* __restrict__ a1) {
    long long tid = (long long)blockIdx.x * blockDim.x + threadIdx.x;
    int e = (int)(tid >> 2);
    int q = (int)(tid & 3);
    if (e >= E) return;
    int is64 = *flag;
    int s = edge_get(ei, e, is64);
    int d = edge_get(ei, (long long)E + e, is64);
    float nrm = dis[s] * dis[d];
    float4 v = *(const float4*)&h1[(long long)s * HID + q * 4];
    float* o = &a1[(long long)d * HID + q * 4];
    atomicAdd(o + 0, nrm * v.x);
    atomicAdd(o + 1, nrm * v.y);
    atomicAdd(o + 2, nrm * v.z);
    atomicAdd(o + 3, nrm * v.w);
}

__global__ void k_agg2(const int* __restrict__ ei, int E, const int* __restrict__ flag,
                       const float* __restrict__ dis, const float* __restrict__ h2,
                       float* __restrict__ a2) {
    long long tid = (long long)blockIdx.x * blockDim.x + threadIdx.x;
    int e = (int)(tid >> 1);
    int q = (int)(tid & 1);
    if (e >= E) return;
    int is64 = *flag;
    int s = edge_get(ei, e, is64);
    int d = edge_get(ei, (long long)E + e, is64);
    float nrm = dis[s] * dis[d];
    int cnt = q ? 3 : 4;
    long long bs = (long long)s * OUTD + q * 4;
    long long bd = (long long)d * OUTD + q * 4;
    #pragma unroll
    for (int j = 0; j < 4; ++j)
        if (j < cnt) atomicAdd(&a2[bd + j], nrm * h2[bs + j]);
}

__global__ void k_lsm(const float* __restrict__ a2, float* __restrict__ out, int n) {
    int r = blockIdx.x * blockDim.x + threadIdx.x;
    if (r >= n) return;
    float v[OUTD];
    #pragma unroll
    for (int j = 0; j < OUTD; ++j) v[j] = a2[(long long)r * OUTD + j];
    float m = v[0];
    #pragma unroll
    for (int j = 1; j < OUTD; ++j) m = fmaxf(m, v[j]);
    float ssum = 0.f;
    #pragma unroll
    for (int j = 0; j < OUTD; ++j) ssum += expf(v[j] - m);
    float l = logf(ssum);
    #pragma unroll
    for (int j = 0; j < OUTD; ++j) out[(long long)r * OUTD + j] = v[j] - m - l;
}

extern "C" void kernel_launch(void* const* d_in, const int* in_sizes, int n_in,
                              void* d_out, int out_size, void* d_ws, size_t ws_size,
                              hipStream_t stream) {
    const float* x  = (const float*)d_in[0];
    const int*   ei = (const int*)d_in[1];
    const float* W1 = (const float*)d_in[2];
    const float* b1 = (const float*)d_in[3];
    const float* W2 = (const float*)d_in[4];
    const float* b2 = (const float*)d_in[5];
    float* out = (float*)d_out;

    const int N = in_sizes[0] / IN_DIM;   // 100000
    const int E = in_sizes[1] / 2;        // 3200000

    const int TPB = 256;
    const int gN  = (N + TPB - 1) / TPB;
    const int gE  = (E + TPB - 1) / TPB;
    const int gG1 = (N + 63) / 64;
    const int NB  = (N + 1023) / 1024;

    float* ws = (float*)d_ws;
    size_t o = 0;
    auto take = [&](size_t cnt) { size_t r = o; o += (cnt + 127) & ~(size_t)127; return r; };

    size_t off_dis  = take((size_t)N);
    size_t off_flag = take(64);
    size_t off_cnt  = take((size_t)N);
    size_t off_rp   = take((size_t)N + 1);
    size_t off_cur  = take((size_t)N);
    size_t off_bs   = take(256);
    size_t off_bo   = take(256);
    size_t off_csr  = take((size_t)E);
    size_t off_h1   = take((size_t)N * HID);
    size_t off_a1   = take((size_t)N * HID);
    size_t off_h2   = take((size_t)N * OUTD);
    size_t need_new = o * sizeof(float);

    if (ws_size >= need_new) {
        float* dis  = ws + off_dis;
        int*   degi = (int*)dis;
        int*   flag = (int*)(ws + off_flag);
        int*   cnt  = (int*)(ws + off_cnt);
        int*   rp   = (int*)(ws + off_rp);
        int*   cur  = (int*)(ws + off_cur);
        int*   bs   = (int*)(ws + off_bs);
        int*   bo   = (int*)(ws + off_bo);
        int*   csr  = (int*)(ws + off_csr);
        float* h1   = ws + off_h1;
        float* a1   = ws + off_a1;
        float* h2   = ws + off_h2;

        k_detect<<<1, 256, 0, stream>>>(ei, flag);
        k_init_new<<<gN, TPB, 0, stream>>>(degi, cnt, N);
        k_hist<<<gE, TPB, 0, stream>>>(ei, E, flag, degi, cnt);
        k_deg_finish<<<gN, TPB, 0, stream>>>(dis, N);
        k_scan1<<<NB, 256, 0, stream>>>(cnt, bs, N);
        k_scan2<<<1, 256, 0, stream>>>(bs, bo, rp, NB, N, E);
        k_scan3<<<NB, 256, 0, stream>>>(cnt, bo, rp, cur, N);
        k_fill<<<gE, TPB, 0, stream>>>(ei, E, flag, cur, csr);
        k_gemm1<<<gG1, 256, 0, stream>>>(x, W1, b1, dis, h1, nullptr, N);
        k_gather1<<<((long long)N * 4 + TPB - 1) / TPB, TPB, 0, stream>>>(rp, csr, dis, h1, a1, N);
        k_gemm2<<<gN, TPB, 0, stream>>>(a1, W2, b2, dis, h2, nullptr, N);
        k_gather2<<<(N + 31) / 32, 256, 0, stream>>>(rp, csr, dis, h2, out, N);
    } else {
        o = 0;
        size_t f_dis  = take((size_t)N);
        size_t f_flag = take(64);
        size_t f_h1   = take((size_t)N * HID);
        size_t f_a1   = take((size_t)N * HID);
        size_t f_h2   = take((size_t)N * OUTD);
        size_t f_a2   = take((size_t)N * OUTD);

        float* dis  = ws + f_dis;
        int*   degi = (int*)dis;
        int*   flag = (int*)(ws + f_flag);
        float* h1   = ws + f_h1;
        float* a1   = ws + f_a1;
        float* h2   = ws + f_h2;
        float* a2   = ws + f_a2;

        int g4E = (int)(((long long)4 * E + TPB - 1) / TPB);
        int g2E = (int)(((long long)2 * E + TPB - 1) / TPB);

        k_detect<<<1, 256, 0, stream>>>(ei, flag);
        k_deg_init<<<gN, TPB, 0, stream>>>(degi, N);
        k_deg_count<<<gE, TPB, 0, stream>>>(ei, E, flag, degi);
        k_deg_finish<<<gN, TPB, 0, stream>>>(dis, N);
        k_gemm1<<<gG1, 256, 0, stream>>>(x, W1, b1, dis, h1, a1, N);
        k_agg1<<<g4E, TPB, 0, stream>>>(ei, E, flag, dis, h1, a1);
        k_gemm2<<<gN, TPB, 0, stream>>>(a1, W2, b2, dis, h2, a2, N);
        k_agg2<<<g2E, TPB, 0, stream>>>(ei, E, flag, dis, h2, a2);
        k_lsm<<<gN, TPB, 0, stream>>>(a2, out, N);
    }
}